// Round 10
// baseline (1442.625 us; speedup 1.0000x reference)
//
#include <hip/hip_runtime.h>

// Inputs: fp32. Outputs: fp32 (established round 3: PASSED).

constexpr int BB = 4;
constexpr int NN = 4096;
constexpr int M1 = 2048;
constexpr int M2 = 512;

typedef float v2f __attribute__((ext_vector_type(2)));

// Exact fp32 squared distance matching numpy's (dx*dx) + (dy*dy), no fma contraction.
__device__ __forceinline__ float d2_exact(float dx, float dy) {
    return __fadd_rn(__fmul_rn(dx, dx), __fmul_rn(dy, dy));
}

// DPP with bound_ctrl=1 (invalid source lanes read 0 — zero keys always lose,
// all real keys > 0). Wave ladder (R0-proven): 0x111/0x112/0x114/0x118
// row_shr 1/2/4/8, 0x142 row_bcast15, 0x143 row_bcast31 -> result at lane 63.
// Quad levels (R6-R9-proven): 0xB1 = quad_perm [1,0,3,2], 0x4E = quad_perm
// [2,3,0,1] — butterfly, result in ALL lanes.
template<int CTRL>
__device__ __forceinline__ unsigned long long dpp64z(unsigned long long v) {
    unsigned lo = (unsigned)__builtin_amdgcn_update_dpp(0, (int)(unsigned)v, CTRL, 0xF, 0xF, true);
    unsigned hi = (unsigned)__builtin_amdgcn_update_dpp(0, (int)(unsigned)(v >> 32), CTRL, 0xF, 0xF, true);
    return ((unsigned long long)hi << 32) | (unsigned long long)lo;
}
// Sorted-triple (top1, top2, top3) combine with CTRL partner triple.
// Merge of two sorted triples -> sorted top-3 of the union (selection
// network; keys unique, zeros from bound_ctrl are neutral). Case-verified:
// (10,7,5)+(8,6,2)->(10,8,7); (10,3,2)+(8,6,2)->(10,8,6);
// (10,9,1)+(8,6,2)->(10,9,8); (5,4,3)+(10,9,8)->(10,9,8); zeros -> identity.
template<int CTRL>
__device__ __forceinline__ void tric(unsigned long long& t1,
                                     unsigned long long& t2,
                                     unsigned long long& t3) {
    unsigned long long b1 = dpp64z<CTRL>(t1);
    unsigned long long b2 = dpp64z<CTRL>(t2);
    unsigned long long b3 = dpp64z<CTRL>(t3);
    bool g = b1 > t1;
    unsigned long long m1 = g ? b1 : t1;
    unsigned long long s1 = g ? t1 : b1;   // losing top
    unsigned long long w2 = g ? b2 : t2;   // winner's 2nd
    unsigned long long w3 = g ? b3 : t3;   // winner's 3rd
    unsigned long long l2 = g ? t2 : b2;   // loser's 2nd
    bool h = w2 > s1;
    unsigned long long m2 = h ? w2 : s1;
    unsigned long long m3 = h ? (w3 > s1 ? w3 : s1)
                             : (w2 > l2 ? w2 : l2);
    t1 = m1; t2 = m2; t3 = m3;
}

// ---------------------------------------------------------------------------
// FPS core (R7-R9 structure, PASSED): 4 waves, 16 pts/lane packed scan,
// float-domain scan (strict > == first-index tie-break), parity buffers,
// single barrier per round, quad-butterfly cross-wave combine. NEW in this
// round: TOP-3 SPECULATION. Per round, emit:
//   w1 always;
//   r1 if d2(r1,w1) >= md_r1              (proven top-2 rule);
//   t1 if additionally d2(t1,w1) >= md_t1 AND d2(t1,r1) >= md_t1.
// Exactness (same induction as top-2): keys only decrease under updates;
// t1's key unchanged by both new centers while all other keys stay below it
// (w1,r1 collapse to md=0 keys), so the reference's next two picks are
// exactly r1 then t1. Unique u64 key = bits(md)<<32 | (0xFFFFFFFF - j)
// gives FIRST-index tie-break throughout; md=0 degenerate cases included.
// ---------------------------------------------------------------------------
template<int M, int PPT>
__device__ __forceinline__ void fps_core(
    const float2* __restrict__ src, const float2* __restrict__ PTSl,
    float2* __restrict__ centl, uint4 (&slkA)[2][4], uint2 (&slkB)[2][4],
    int tid, int lane, int wv)
{
#pragma clang fp contract(off)
    constexpr int PP2 = PPT / 2;
    v2f px2[PP2], py2[PP2], md2[PP2];
#pragma unroll
    for (int k = 0; k < PP2; ++k) {
        float2 a = src[tid + (2 * k) * 256];
        float2 b = src[tid + (2 * k + 1) * 256];
        px2[k] = (v2f){a.x, b.x};
        py2[k] = (v2f){a.y, b.y};
        md2[k] = (v2f){1e10f, 1e10f};
    }
    float2 c0 = src[0];
    if (tid == 0) centl[0] = c0;

    unsigned baseu = 0xFFFFFFFFu - (unsigned)tid;
    float c1x = c0.x, c1y = c0.y;
    float c2x = 0.0f, c2y = 0.0f, c3x = 0.0f, c3y = 0.0f;
    bool two = false, three = false;
    int it = 1;
    unsigned rc = 0;
    while (it < M) {
        int par = (int)(rc & 1u); ++rc;
        // ---- packed md update by pending center(s); rn per half == scalar rn
        v2f vcx = (v2f){c1x, c1x}, vcy = (v2f){c1y, c1y};
#pragma unroll
        for (int k = 0; k < PP2; ++k) {
            v2f dx = px2[k] - vcx, dy = py2[k] - vcy;
            v2f d2 = (dx * dx) + (dy * dy);          // contract off => exact
            md2[k] = __builtin_elementwise_min(md2[k], d2);
        }
        if (two) {
            v2f wcx = (v2f){c2x, c2x}, wcy = (v2f){c2y, c2y};
#pragma unroll
            for (int k = 0; k < PP2; ++k) {
                v2f dx = px2[k] - wcx, dy = py2[k] - wcy;
                v2f d2 = (dx * dx) + (dy * dy);
                md2[k] = __builtin_elementwise_min(md2[k], d2);
            }
        }
        if (three) {
            v2f tcx = (v2f){c3x, c3x}, tcy = (v2f){c3y, c3y};
#pragma unroll
            for (int k = 0; k < PP2; ++k) {
                v2f dx = px2[k] - tcx, dy = py2[k] - tcy;
                v2f d2 = (dx * dx) + (dy * dy);
                md2[k] = __builtin_elementwise_min(md2[k], d2);
            }
        }
        // ---- per-lane top-3, float domain (strict > == first-index ties;
        //      g1 => g2 => g3 since t1f >= t2f >= t3f)
        float t1f = -1.0f, t2f = -1.0f, t3f = -1.0f;
        unsigned i1 = 0u, i2 = 0u, i3 = 0u;
#pragma unroll
        for (int s = 0; s < PPT; ++s) {
            float mq = (s & 1) ? md2[s >> 1].y : md2[s >> 1].x;
            unsigned io = baseu - (unsigned)(s * 256);
            bool g1 = mq > t1f;
            bool g2 = mq > t2f;
            bool g3 = mq > t3f;
            t3f = g2 ? t2f : (g3 ? mq : t3f);
            i3  = g2 ? i2  : (g3 ? io : i3);
            t2f = g1 ? t1f : (g2 ? mq : t2f);
            i2  = g1 ? i1  : (g2 ? io : i2);
            t1f = g1 ? mq : t1f;
            i1  = g1 ? io : i1;
        }
        unsigned long long t1 =
            ((unsigned long long)__float_as_uint(t1f) << 32) | (unsigned long long)i1;
        unsigned long long t2 =
            ((unsigned long long)__float_as_uint(t2f) << 32) | (unsigned long long)i2;
        unsigned long long t3 =
            ((unsigned long long)__float_as_uint(t3f) << 32) | (unsigned long long)i3;
        // ---- wave triple ladder -> lane 63 ----
        tric<0x111>(t1, t2, t3); tric<0x112>(t1, t2, t3);
        tric<0x114>(t1, t2, t3); tric<0x118>(t1, t2, t3);
        tric<0x142>(t1, t2, t3); tric<0x143>(t1, t2, t3);
        if (lane == 63) {
            slkA[par][wv] = make_uint4((unsigned)t1, (unsigned)(t1 >> 32),
                                       (unsigned)t2, (unsigned)(t2 >> 32));
            slkB[par][wv] = make_uint2((unsigned)t3, (unsigned)(t3 >> 32));
        }
        __syncthreads();                   // the only barrier per round
        // ---- cross-wave quad butterfly: all lanes -> global sorted triple
        uint4 eA = slkA[par][lane & 3];
        uint2 eB = slkB[par][lane & 3];
        unsigned long long a1 = ((unsigned long long)eA.y << 32) | (unsigned long long)eA.x;
        unsigned long long a2 = ((unsigned long long)eA.w << 32) | (unsigned long long)eA.z;
        unsigned long long a3 = ((unsigned long long)eB.y << 32) | (unsigned long long)eB.x;
        tric<0xB1>(a1, a2, a3);            // quad xor1
        tric<0x4E>(a1, a2, a3);            // quad xor2
        int jw = (int)(0xFFFFFFFFu - (unsigned)a1);
        int jr = (int)(0xFFFFFFFFu - (unsigned)a2);
        int jt = (int)(0xFFFFFFFFu - (unsigned)a3);
        float mdr = __uint_as_float((unsigned)(a2 >> 32));
        float mdt = __uint_as_float((unsigned)(a3 >> 32));
        float2 wpt = PTSl[jw];             // uniform broadcast LDS reads
        float2 rpt = PTSl[jr];
        float2 tpt = PTSl[jt];
        float ddx = rpt.x - wpt.x, ddy = rpt.y - wpt.y;
        float dd = (ddx * ddx) + (ddy * ddy);    // contract off => exact rn
        float twx = tpt.x - wpt.x, twy = tpt.y - wpt.y;
        float dtw = (twx * twx) + (twy * twy);
        float trx = tpt.x - rpt.x, try_ = tpt.y - rpt.y;
        float dtr = (trx * trx) + (try_ * try_);
        bool dbl  = (it + 1 < M) && (dd >= mdr);           // uniform
        bool trip = dbl && (it + 2 < M) && (dtw >= mdt) && (dtr >= mdt);
        if (tid == 0) {
            centl[it] = wpt;
            if (dbl)  centl[it + 1] = rpt;
            if (trip) centl[it + 2] = tpt;
        }
        c1x = wpt.x; c1y = wpt.y;
        c2x = rpt.x; c2y = rpt.y;
        c3x = tpt.x; c3y = tpt.y;
        two = dbl;
        three = trip;
        it += trip ? 3 : (dbl ? 2 : 1);
    }
}

// ---------------------------------------------------------------------------
// Kernel 1: blocks [0, BB) run FPS STAGE 1 (4096 -> 2048) -> p1; blocks
// [BB, BB + BB*NN/4) run lf/y1 dense math on idle CUs (R7-R9-proven).
// ---------------------------------------------------------------------------
__global__ __launch_bounds__(256, 1) void k_fps1(
    const float2* __restrict__ pos, float* __restrict__ p1out,
    const float* __restrict__ zones,
    const float* __restrict__ W1, const float* __restrict__ b1,
    const float* __restrict__ W2, const float* __restrict__ b2,
    const float* __restrict__ c1W, const float* __restrict__ c1b,
    float* __restrict__ out_lf, float* __restrict__ y1)
{
    __shared__ float2 PTS[NN];            // 32 KB (fps gather source / lf scratch)
    __shared__ float2 cent1[M1];          // 16 KB
    __shared__ uint4 slkA[2][4];          // parity triple buffers
    __shared__ uint2 slkB[2][4];
    int tid = threadIdx.x, lane = tid & 63, wv = tid >> 6;

    if (blockIdx.x >= (unsigned)BB) {
        // ---------------- lf / y1 path (verbatim R7-R9, LDS aliased) ------
        float* sh = (float*)PTS;          // sh[4][64]
        float* sl = sh + 256;             // sl[4][64]
        int p = tid >> 6, f = tid & 63;
        size_t pt = (size_t)(blockIdx.x - BB) * 4 + p;
        float2 xv = pos[pt];
        float hid = tanhf(xv.x * W1[f] + xv.y * W1[64 + f] + b1[f]);
        sh[p * 64 + f] = hid;
        __syncthreads();
        float acc = b2[f];
#pragma unroll
        for (int c = 0; c < 64; ++c) acc += sh[p * 64 + c] * W2[c * 64 + f];
        float lf = tanhf(acc);
        sl[p * 64 + f] = lf;
        out_lf[pt * 64 + f] = lf;
        __syncthreads();
        float acc2 = c1b[f] + zones[pt] * c1W[64 * 64 + f]
                   + xv.x * c1W[65 * 64 + f] + xv.y * c1W[66 * 64 + f];
#pragma unroll
        for (int c = 0; c < 64; ++c) acc2 += sl[p * 64 + c] * c1W[c * 64 + f];
        y1[pt * 64 + f] = acc2;
        return;
    }

    // -------------------- FPS stage 1 (blocks 0..BB-1) --------------------
    const float2* p = pos + (size_t)blockIdx.x * NN;
    for (int i = tid; i < NN; i += 256) PTS[i] = p[i];
    __syncthreads();                      // PTS complete

    fps_core<M1, NN / 256>(p, PTS, cent1, slkA, slkB, tid, lane, wv);
    __syncthreads();                      // cent1 complete
    float2* o1 = (float2*)(p1out + (size_t)blockIdx.x * M1 * 2);
    for (int i = tid; i < M1; i += 256) o1[i] = cent1[i];
}

// ---------------------------------------------------------------------------
// Kernel 2: blocks [0, BB) run FPS STAGE 2 (2048 -> 512) -> p2; blocks
// [BB, BB + M1*BB) each compute ONE sa1 center row h1[crow] and — when
// fuse_y2 != 0 (workspace permits a non-aliased y2) — immediately the y2 row
// with k_y2's exact addition order, hidden under the stage-2 serial chain.
// ---------------------------------------------------------------------------
__global__ __launch_bounds__(256) void k_fps2_sa1(
    const float2* __restrict__ x, const float* __restrict__ p1,
    const float* __restrict__ y1, const float* __restrict__ c1W,
    const float* __restrict__ c2W, const float* __restrict__ c2b,
    float* __restrict__ p2out, float* __restrict__ h1,
    float* __restrict__ y2, int fuse_y2)
{
    __shared__ float2 PTS2[M1];           // 16 KB stage2 points
    __shared__ float2 cent2[M2];          // 4 KB
    __shared__ uint4 slkA[2][4];
    __shared__ uint2 slkB[2][4];
    __shared__ int cnt;
    __shared__ int list[NN];              // 16 KB sa candidate list
    __shared__ float h1row[64];           // staged h1 row for fused y2
    int tid = threadIdx.x, lane = tid & 63, wv = tid >> 6;

    if (blockIdx.x < (unsigned)BB) {
        // -------------------- FPS stage 2 ---------------------------------
        const float2* p1b = (const float2*)(p1 + (size_t)blockIdx.x * M1 * 2);
        for (int i = tid; i < M1; i += 256) PTS2[i] = p1b[i];
        __syncthreads();                  // PTS2 complete
        fps_core<M2, M1 / 256>(PTS2, PTS2, cent2, slkA, slkB, tid, lane, wv);
        __syncthreads();                  // cent2 complete
        float2* o2 = (float2*)(p2out + (size_t)blockIdx.x * M2 * 2);
        for (int i = tid; i < M2; i += 256) o2[i] = cent2[i];
        return;
    }

    // -------------------- sa1: one center per block -----------------------
    int idx = (int)blockIdx.x - BB;       // 0 .. M1*BB-1
    int b = idx >> 11;                    // / M1 (M1 == 2048)
    size_t crow = (size_t)idx;            // == b*M1 + (idx % M1)
    if (tid == 0) cnt = 0;
    __syncthreads();
    float cx = p1[crow * 2], cy = p1[crow * 2 + 1];
    const float2* cp = x + (size_t)b * NN;
    for (int j = tid; j < NN; j += 256) {
        float2 pj = cp[j];
        float d2 = d2_exact(pj.x - cx, pj.y - cy);
        if (d2 <= 0.25f) { int t = atomicAdd(&cnt, 1); list[t] = j; }
    }
    __syncthreads();
    int n = cnt;
    for (int f = tid; f < 64; f += 256) {
        float m = -3.0e38f;
        for (int t = 0; t < n; ++t)
            m = fmaxf(m, y1[((size_t)b * NN + list[t]) * 64 + f]);
        float ct = cx * c1W[(size_t)65 * 64 + f] + cy * c1W[(size_t)66 * 64 + f];
        float h1v = m - ct;
        if (fuse_y2) h1row[f] = h1v;
        else h1[crow * 64 + f] = h1v;
    }
    if (fuse_y2) {                        // uniform kernel arg -> safe barrier
        __syncthreads();                  // h1row complete
        // exact k_y2 arithmetic/order: (bb + px*W64) + py*W65, then c=0..63
        for (int f = tid; f < 128; f += 256) {
            float acc = c2b[f] + cx * c2W[64 * 128 + f]
                      + cy * c2W[65 * 128 + f];
#pragma unroll
            for (int c = 0; c < 64; ++c) acc += h1row[c] * c2W[c * 128 + f];
            y2[crow * 128 + f] = acc;
        }
    }
}

// ---------------------------------------------------------------------------
// Set abstraction (stage 2): h[i,f] = max_{j: d2<=r2} y[j,f] - ctr_i @ W_rel.
// ---------------------------------------------------------------------------
__global__ __launch_bounds__(256) void k_sa(
    const float2* __restrict__ candpos, const float* __restrict__ y,
    const float* __restrict__ ctr, const float* __restrict__ W,
    int NP, int F, int relrow, float r2, float* __restrict__ hout)
{
    __shared__ int cnt;
    __shared__ int list[4096];
    int tid = threadIdx.x;
    int b = blockIdx.y;
    size_t crow = (size_t)b * gridDim.x + blockIdx.x;
    if (tid == 0) cnt = 0;
    __syncthreads();
    float cx = ctr[crow * 2], cy = ctr[crow * 2 + 1];
    const float2* cp = candpos + (size_t)b * NP;
    for (int j = tid; j < NP; j += 256) {
        float2 pj = cp[j];
        float d2 = d2_exact(pj.x - cx, pj.y - cy);
        if (d2 <= r2) { int t = atomicAdd(&cnt, 1); list[t] = j; }
    }
    __syncthreads();
    int n = cnt;
    for (int f = tid; f < F; f += 256) {
        float m = -3.0e38f;
        for (int t = 0; t < n; ++t)
            m = fmaxf(m, y[((size_t)b * NP + list[t]) * F + f]);
        float ct = cx * W[(size_t)relrow * F + f] + cy * W[(size_t)(relrow + 1) * F + f];
        hout[crow * F + f] = m - ct;
    }
}

// ---------------------------------------------------------------------------
// y2[j,f] = h1_j @ c2W[0:64] + pos_j @ c2W[64:66] + c2b  (fallback only)
// ---------------------------------------------------------------------------
__global__ __launch_bounds__(128) void k_y2(
    const float* __restrict__ h1, const float* __restrict__ p1,
    const float* __restrict__ W, const float* __restrict__ bb,
    float* __restrict__ y2)
{
    __shared__ float sh[64];
    size_t row = blockIdx.x;
    int f = threadIdx.x;
    if (f < 64) sh[f] = h1[row * 64 + f];
    __syncthreads();
    float acc = bb[f] + p1[row * 2] * W[64 * 128 + f]
              + p1[row * 2 + 1] * W[65 * 128 + f];
#pragma unroll
    for (int c = 0; c < 64; ++c) acc += sh[c] * W[c * 128 + f];
    y2[row * 128 + f] = acc;
}

// ---------------------------------------------------------------------------
// g[i,f] = [h2_i, pos_i] @ c3W + c3b; partial max over 8 rows/thread.
// ---------------------------------------------------------------------------
__global__ __launch_bounds__(256) void k_g(
    const float* __restrict__ h2, const float* __restrict__ p2,
    const float* __restrict__ W3, const float* __restrict__ b3,
    float* __restrict__ part)
{
    int f = blockIdx.x * 256 + threadIdx.x;
    int b = blockIdx.z;
    int i0 = blockIdx.y * 8;
    float acc[8];
    float bbv = b3[f];
#pragma unroll
    for (int ii = 0; ii < 8; ++ii) acc[ii] = bbv;
    const float* hrow = h2 + ((size_t)b * M2 + i0) * 128;
    for (int c = 0; c < 128; ++c) {
        float w = W3[(size_t)c * 1024 + f];
#pragma unroll
        for (int ii = 0; ii < 8; ++ii) acc[ii] += hrow[ii * 128 + c] * w;
    }
    float wx = W3[(size_t)128 * 1024 + f];
    float wy = W3[(size_t)129 * 1024 + f];
    const float* prow = p2 + ((size_t)b * M2 + i0) * 2;
    float m = -3.0e38f;
#pragma unroll
    for (int ii = 0; ii < 8; ++ii) {
        float g = acc[ii] + prow[ii * 2] * wx + prow[ii * 2 + 1] * wy;
        m = fmaxf(m, g);
    }
    part[((size_t)b * 64 + blockIdx.y) * 1024 + f] = m;
}

__global__ __launch_bounds__(256) void k_gmax(const float* __restrict__ part,
                                              float* __restrict__ outg)
{
    int f = blockIdx.x * 256 + threadIdx.x;   // 0..4095
    int b = f >> 10, fl = f & 1023;
    float m = -3.0e38f;
#pragma unroll 8
    for (int ig = 0; ig < 64; ++ig)
        m = fmaxf(m, part[((size_t)b * 64 + ig) * 1024 + fl]);
    outg[f] = m;
}

extern "C" void kernel_launch(void* const* d_in, const int* in_sizes, int n_in,
                              void* d_out, int out_size, void* d_ws, size_t ws_size,
                              hipStream_t stream)
{
    const float* x    = (const float*)d_in[0];
    const float* zon  = (const float*)d_in[1];
    const float* lfW1 = (const float*)d_in[2];
    const float* lfb1 = (const float*)d_in[3];
    const float* lfW2 = (const float*)d_in[4];
    const float* lfb2 = (const float*)d_in[5];
    const float* c1W  = (const float*)d_in[6];
    const float* c1b  = (const float*)d_in[7];
    const float* c2W  = (const float*)d_in[8];
    const float* c2b  = (const float*)d_in[9];
    const float* c3W  = (const float*)d_in[10];
    const float* c3b  = (const float*)d_in[11];
    float* out = (float*)d_out;

    // Sizes (bytes)
    const size_t szY1 = (size_t)BB * NN * 64 * 4;    // 4 MB
    const size_t szP1 = (size_t)BB * M1 * 2 * 4;
    const size_t szH1 = (size_t)BB * M1 * 64 * 4;    // 2 MB
    const size_t szY2 = (size_t)BB * M1 * 128 * 4;   // 4 MB
    const size_t szP2 = (size_t)BB * M2 * 2 * 4;
    const size_t szH2 = (size_t)BB * M2 * 128 * 4;   // 1 MB

    // Fused layout needs y2 NOT aliasing y1 (sa1 blocks read y1 while y2 is
    // written). Fall back to the R8 layout + k_y2 when ws is too small.
    bool fuse = ws_size >= szY1 + szP1 + szY2 + szP2 + szH2;

    char* w = (char*)d_ws;
    float* y1 = (float*)w;                     w += szY1;   // also reused: part
    float* p1 = (float*)w;                     w += szP1;
    float *h1, *y2;
    if (fuse) {
        h1 = nullptr;
        y2 = (float*)w;                        w += szY2;
    } else {
        h1 = (float*)w;                        w += szH1;
        y2 = y1;                               // R8 alias (y1 dead by k_y2)
    }
    float* p2 = (float*)w;                     w += szP2;
    float* h2 = (float*)w;                     w += szH2;
    float* part = y1;                          // y1 dead after kernel 2

    // Stage-1 FPS (blocks 0..3) overlaps lf/y1 (blocks 4..4099).
    k_fps1<<<BB + BB * NN / 4, 256, 0, stream>>>(
        (const float2*)x, p1, zon, lfW1, lfb1, lfW2, lfb2, c1W, c1b, out, y1);
    // Stage-2 FPS (blocks 0..3) overlaps sa1 (+fused y2) (blocks 4..8195).
    k_fps2_sa1<<<BB + BB * M1, 256, 0, stream>>>(
        (const float2*)x, p1, y1, c1W, c2W, c2b, p2,
        fuse ? p1 /*unused*/ : h1, y2, fuse ? 1 : 0);
    if (!fuse)
        k_y2<<<BB * M1, 128, 0, stream>>>(h1, p1, c2W, c2b, y2);
    k_sa<<<dim3(M2, BB), 256, 0, stream>>>((const float2*)p1, y2, p2, c2W,
                                           M1, 128, 64, 1.0f, h2);
    k_g<<<dim3(4, 64, BB), 256, 0, stream>>>(h2, p2, c3W, c3b, part);
    k_gmax<<<16, 256, 0, stream>>>(part, out + (size_t)BB * NN * 64);
}

// Round 11
// 1427.942 us; speedup vs baseline: 1.0103x; 1.0103x over previous
//
#include <hip/hip_runtime.h>

// Inputs: fp32. Outputs: fp32 (established round 3: PASSED).

constexpr int BB = 4;
constexpr int NN = 4096;
constexpr int M1 = 2048;
constexpr int M2 = 512;

typedef float v2f __attribute__((ext_vector_type(2)));

// Exact fp32 squared distance matching numpy's (dx*dx) + (dy*dy), no fma contraction.
__device__ __forceinline__ float d2_exact(float dx, float dy) {
    return __fadd_rn(__fmul_rn(dx, dx), __fmul_rn(dy, dy));
}

// DPP with bound_ctrl=1 (invalid source lanes read 0 — zero keys always lose,
// all real keys > 0). Wave ladder (R0-proven): 0x111/0x112/0x114/0x118
// row_shr 1/2/4/8, 0x142 row_bcast15, 0x143 row_bcast31 -> result at lane 63.
// Quad levels (R6-R10-proven): 0xB1 = quad_perm [1,0,3,2], 0x4E = quad_perm
// [2,3,0,1] — butterfly, result in ALL lanes.
template<int CTRL>
__device__ __forceinline__ unsigned long long dpp64z(unsigned long long v) {
    unsigned lo = (unsigned)__builtin_amdgcn_update_dpp(0, (int)(unsigned)v, CTRL, 0xF, 0xF, true);
    unsigned hi = (unsigned)__builtin_amdgcn_update_dpp(0, (int)(unsigned)(v >> 32), CTRL, 0xF, 0xF, true);
    return ((unsigned long long)hi << 32) | (unsigned long long)lo;
}
// (top1, top2) u64 pair combine with CTRL partner pair. Keys unique. (Proven.)
template<int CTRL>
__device__ __forceinline__ void pairc(unsigned long long& t1, unsigned long long& t2) {
    unsigned long long o1 = dpp64z<CTRL>(t1);
    unsigned long long o2 = dpp64z<CTRL>(t2);
    bool g = o1 > t1;
    unsigned long long m1 = g ? o1 : t1;
    unsigned long long sm = g ? t1 : o1;
    unsigned long long cn = g ? o2 : t2;
    t2 = cn > sm ? cn : sm;
    t1 = m1;
}
// Sorted-triple (top1, top2, top3) combine with CTRL partner triple (R10-
// proven). Merge of two sorted triples -> sorted top-3 of the union.
template<int CTRL>
__device__ __forceinline__ void tric(unsigned long long& t1,
                                     unsigned long long& t2,
                                     unsigned long long& t3) {
    unsigned long long b1 = dpp64z<CTRL>(t1);
    unsigned long long b2 = dpp64z<CTRL>(t2);
    unsigned long long b3 = dpp64z<CTRL>(t3);
    bool g = b1 > t1;
    unsigned long long m1 = g ? b1 : t1;
    unsigned long long s1 = g ? t1 : b1;   // losing top
    unsigned long long w2 = g ? b2 : t2;   // winner's 2nd
    unsigned long long w3 = g ? b3 : t3;   // winner's 3rd
    unsigned long long l2 = g ? t2 : b2;   // loser's 2nd
    bool h = w2 > s1;
    unsigned long long m2 = h ? w2 : s1;
    unsigned long long m3 = h ? (w3 > s1 ? w3 : s1)
                             : (w2 > l2 ? w2 : l2);
    t1 = m1; t2 = m2; t3 = m3;
}

// ---------------------------------------------------------------------------
// FPS core, hybrid speculation depth (S3 template):
//   S3 = true  -> TOP-3 speculation (R10 path, PASSED; wins in stage 1 where
//                 candidates are spread and p(triple) is high enough).
//   S3 = false -> TOP-2 speculation (R9 path, PASSED; stage 2's post-FPS
//                 near-uniform points make the 3rd candidate rarely emittable,
//                 so the triple-ladder tax loses there — R10 measured).
// Common structure (R7+): 4 waves, 16 pts/lane packed scan, float-domain
// top-k scan (strict > == first-index tie-break), parity buffers, single
// barrier per round, quad-butterfly cross-wave combine.
// Bit-exact vs reference scan:
//   md[j] = fmin(md[j], d2_exact(j, c)); argmax w/ FIRST-index tie-break via
//   unique u64 key = bits(md)<<32 | (0xFFFFFFFF - j).
// Emit rules (induction on "keys only decrease"):
//   r1 if d2(r1,w1) >= md_r1;  t1 (S3) if additionally d2(t1,w1) >= md_t1
//   AND d2(t1,r1) >= md_t1.
// ---------------------------------------------------------------------------
template<int M, int PPT, bool S3>
__device__ __forceinline__ void fps_core(
    const float2* __restrict__ src, const float2* __restrict__ PTSl,
    float2* __restrict__ centl, uint4 (&slkA)[2][4], uint2 (&slkB)[2][4],
    int tid, int lane, int wv)
{
#pragma clang fp contract(off)
    constexpr int PP2 = PPT / 2;
    v2f px2[PP2], py2[PP2], md2[PP2];
#pragma unroll
    for (int k = 0; k < PP2; ++k) {
        float2 a = src[tid + (2 * k) * 256];
        float2 b = src[tid + (2 * k + 1) * 256];
        px2[k] = (v2f){a.x, b.x};
        py2[k] = (v2f){a.y, b.y};
        md2[k] = (v2f){1e10f, 1e10f};
    }
    float2 c0 = src[0];
    if (tid == 0) centl[0] = c0;

    unsigned baseu = 0xFFFFFFFFu - (unsigned)tid;
    float c1x = c0.x, c1y = c0.y;
    float c2x = 0.0f, c2y = 0.0f, c3x = 0.0f, c3y = 0.0f;
    bool two = false, three = false;
    int it = 1;
    unsigned rc = 0;
    while (it < M) {
        int par = (int)(rc & 1u); ++rc;
        // ---- packed md update by pending center(s); rn per half == scalar rn
        v2f vcx = (v2f){c1x, c1x}, vcy = (v2f){c1y, c1y};
#pragma unroll
        for (int k = 0; k < PP2; ++k) {
            v2f dx = px2[k] - vcx, dy = py2[k] - vcy;
            v2f d2 = (dx * dx) + (dy * dy);          // contract off => exact
            md2[k] = __builtin_elementwise_min(md2[k], d2);
        }
        if (two) {
            v2f wcx = (v2f){c2x, c2x}, wcy = (v2f){c2y, c2y};
#pragma unroll
            for (int k = 0; k < PP2; ++k) {
                v2f dx = px2[k] - wcx, dy = py2[k] - wcy;
                v2f d2 = (dx * dx) + (dy * dy);
                md2[k] = __builtin_elementwise_min(md2[k], d2);
            }
        }
        if (S3 && three) {
            v2f tcx = (v2f){c3x, c3x}, tcy = (v2f){c3y, c3y};
#pragma unroll
            for (int k = 0; k < PP2; ++k) {
                v2f dx = px2[k] - tcx, dy = py2[k] - tcy;
                v2f d2 = (dx * dx) + (dy * dy);
                md2[k] = __builtin_elementwise_min(md2[k], d2);
            }
        }

        if constexpr (S3) {
            // ---- per-lane top-3, float domain (g1 => g2 => g3) ----
            float t1f = -1.0f, t2f = -1.0f, t3f = -1.0f;
            unsigned i1 = 0u, i2 = 0u, i3 = 0u;
#pragma unroll
            for (int s = 0; s < PPT; ++s) {
                float mq = (s & 1) ? md2[s >> 1].y : md2[s >> 1].x;
                unsigned io = baseu - (unsigned)(s * 256);
                bool g1 = mq > t1f;
                bool g2 = mq > t2f;
                bool g3 = mq > t3f;
                t3f = g2 ? t2f : (g3 ? mq : t3f);
                i3  = g2 ? i2  : (g3 ? io : i3);
                t2f = g1 ? t1f : (g2 ? mq : t2f);
                i2  = g1 ? i1  : (g2 ? io : i2);
                t1f = g1 ? mq : t1f;
                i1  = g1 ? io : i1;
            }
            unsigned long long t1 =
                ((unsigned long long)__float_as_uint(t1f) << 32) | (unsigned long long)i1;
            unsigned long long t2 =
                ((unsigned long long)__float_as_uint(t2f) << 32) | (unsigned long long)i2;
            unsigned long long t3 =
                ((unsigned long long)__float_as_uint(t3f) << 32) | (unsigned long long)i3;
            // ---- wave triple ladder -> lane 63 ----
            tric<0x111>(t1, t2, t3); tric<0x112>(t1, t2, t3);
            tric<0x114>(t1, t2, t3); tric<0x118>(t1, t2, t3);
            tric<0x142>(t1, t2, t3); tric<0x143>(t1, t2, t3);
            if (lane == 63) {
                slkA[par][wv] = make_uint4((unsigned)t1, (unsigned)(t1 >> 32),
                                           (unsigned)t2, (unsigned)(t2 >> 32));
                slkB[par][wv] = make_uint2((unsigned)t3, (unsigned)(t3 >> 32));
            }
            __syncthreads();               // the only barrier per round
            // ---- cross-wave quad butterfly -> global sorted triple ----
            uint4 eA = slkA[par][lane & 3];
            uint2 eB = slkB[par][lane & 3];
            unsigned long long a1 = ((unsigned long long)eA.y << 32) | (unsigned long long)eA.x;
            unsigned long long a2 = ((unsigned long long)eA.w << 32) | (unsigned long long)eA.z;
            unsigned long long a3 = ((unsigned long long)eB.y << 32) | (unsigned long long)eB.x;
            tric<0xB1>(a1, a2, a3);
            tric<0x4E>(a1, a2, a3);
            int jw = (int)(0xFFFFFFFFu - (unsigned)a1);
            int jr = (int)(0xFFFFFFFFu - (unsigned)a2);
            int jt = (int)(0xFFFFFFFFu - (unsigned)a3);
            float mdr = __uint_as_float((unsigned)(a2 >> 32));
            float mdt = __uint_as_float((unsigned)(a3 >> 32));
            float2 wpt = PTSl[jw];         // uniform broadcast LDS reads
            float2 rpt = PTSl[jr];
            float2 tpt = PTSl[jt];
            float ddx = rpt.x - wpt.x, ddy = rpt.y - wpt.y;
            float dd = (ddx * ddx) + (ddy * ddy);    // contract off => exact
            float twx = tpt.x - wpt.x, twy = tpt.y - wpt.y;
            float dtw = (twx * twx) + (twy * twy);
            float trx = tpt.x - rpt.x, try_ = tpt.y - rpt.y;
            float dtr = (trx * trx) + (try_ * try_);
            bool dbl  = (it + 1 < M) && (dd >= mdr);           // uniform
            bool trip = dbl && (it + 2 < M) && (dtw >= mdt) && (dtr >= mdt);
            if (tid == 0) {
                centl[it] = wpt;
                if (dbl)  centl[it + 1] = rpt;
                if (trip) centl[it + 2] = tpt;
            }
            c1x = wpt.x; c1y = wpt.y;
            c2x = rpt.x; c2y = rpt.y;
            c3x = tpt.x; c3y = tpt.y;
            two = dbl;
            three = trip;
            it += trip ? 3 : (dbl ? 2 : 1);
        } else {
            // ---- per-lane top-2, float domain (verbatim R9, PASSED) ----
            float t1f = -1.0f, t2f = -1.0f;
            unsigned i1 = 0u, i2 = 0u;
#pragma unroll
            for (int s = 0; s < PPT; ++s) {
                float mq = (s & 1) ? md2[s >> 1].y : md2[s >> 1].x;
                unsigned io = baseu - (unsigned)(s * 256);
                bool g1 = mq > t1f;
                bool g2 = mq > t2f;
                t2f = g1 ? t1f : (g2 ? mq : t2f);
                i2  = g1 ? i1  : (g2 ? io : i2);
                t1f = g1 ? mq : t1f;
                i1  = g1 ? io : i1;
            }
            unsigned long long t1 =
                ((unsigned long long)__float_as_uint(t1f) << 32) | (unsigned long long)i1;
            unsigned long long t2 =
                ((unsigned long long)__float_as_uint(t2f) << 32) | (unsigned long long)i2;
            // ---- wave pair ladder -> lane 63 ----
            pairc<0x111>(t1, t2); pairc<0x112>(t1, t2); pairc<0x114>(t1, t2);
            pairc<0x118>(t1, t2); pairc<0x142>(t1, t2); pairc<0x143>(t1, t2);
            if (lane == 63)
                slkA[par][wv] = make_uint4((unsigned)t1, (unsigned)(t1 >> 32),
                                           (unsigned)t2, (unsigned)(t2 >> 32));
            __syncthreads();               // the only barrier per round
            // ---- cross-wave quad butterfly -> global (top1, top2) ----
            uint4 e = slkA[par][lane & 3];
            unsigned long long a1 = ((unsigned long long)e.y << 32) | (unsigned long long)e.x;
            unsigned long long a2 = ((unsigned long long)e.w << 32) | (unsigned long long)e.z;
            pairc<0xB1>(a1, a2);
            pairc<0x4E>(a1, a2);
            int jw = (int)(0xFFFFFFFFu - (unsigned)a1);
            int jr = (int)(0xFFFFFFFFu - (unsigned)a2);
            float mdr = __uint_as_float((unsigned)(a2 >> 32));
            float2 wpt = PTSl[jw];         // uniform broadcast LDS reads
            float2 rpt = PTSl[jr];
            float ddx = rpt.x - wpt.x, ddy = rpt.y - wpt.y;
            float dd = (ddx * ddx) + (ddy * ddy);    // contract off => exact
            bool dbl = (it + 1 < M) && (dd >= mdr);  // uniform
            if (tid == 0) { centl[it] = wpt; if (dbl) centl[it + 1] = rpt; }
            c1x = wpt.x; c1y = wpt.y; c2x = rpt.x; c2y = rpt.y;
            two = dbl;
            it += dbl ? 2 : 1;
        }
    }
}

// ---------------------------------------------------------------------------
// Kernel 1: blocks [0, BB) run FPS STAGE 1 (4096 -> 2048, TOP-3) -> p1;
// blocks [BB, BB + BB*NN/4) run lf/y1 dense math on idle CUs (R7-R10-proven).
// ---------------------------------------------------------------------------
__global__ __launch_bounds__(256, 1) void k_fps1(
    const float2* __restrict__ pos, float* __restrict__ p1out,
    const float* __restrict__ zones,
    const float* __restrict__ W1, const float* __restrict__ b1,
    const float* __restrict__ W2, const float* __restrict__ b2,
    const float* __restrict__ c1W, const float* __restrict__ c1b,
    float* __restrict__ out_lf, float* __restrict__ y1)
{
    __shared__ float2 PTS[NN];            // 32 KB (fps gather source / lf scratch)
    __shared__ float2 cent1[M1];          // 16 KB
    __shared__ uint4 slkA[2][4];          // parity buffers
    __shared__ uint2 slkB[2][4];
    int tid = threadIdx.x, lane = tid & 63, wv = tid >> 6;

    if (blockIdx.x >= (unsigned)BB) {
        // ---------------- lf / y1 path (verbatim R7-R10, LDS aliased) -----
        float* sh = (float*)PTS;          // sh[4][64]
        float* sl = sh + 256;             // sl[4][64]
        int p = tid >> 6, f = tid & 63;
        size_t pt = (size_t)(blockIdx.x - BB) * 4 + p;
        float2 xv = pos[pt];
        float hid = tanhf(xv.x * W1[f] + xv.y * W1[64 + f] + b1[f]);
        sh[p * 64 + f] = hid;
        __syncthreads();
        float acc = b2[f];
#pragma unroll
        for (int c = 0; c < 64; ++c) acc += sh[p * 64 + c] * W2[c * 64 + f];
        float lf = tanhf(acc);
        sl[p * 64 + f] = lf;
        out_lf[pt * 64 + f] = lf;
        __syncthreads();
        float acc2 = c1b[f] + zones[pt] * c1W[64 * 64 + f]
                   + xv.x * c1W[65 * 64 + f] + xv.y * c1W[66 * 64 + f];
#pragma unroll
        for (int c = 0; c < 64; ++c) acc2 += sl[p * 64 + c] * c1W[c * 64 + f];
        y1[pt * 64 + f] = acc2;
        return;
    }

    // -------------------- FPS stage 1 (blocks 0..BB-1), TOP-3 -------------
    const float2* p = pos + (size_t)blockIdx.x * NN;
    for (int i = tid; i < NN; i += 256) PTS[i] = p[i];
    __syncthreads();                      // PTS complete

    fps_core<M1, NN / 256, true>(p, PTS, cent1, slkA, slkB, tid, lane, wv);
    __syncthreads();                      // cent1 complete
    float2* o1 = (float2*)(p1out + (size_t)blockIdx.x * M1 * 2);
    for (int i = tid; i < M1; i += 256) o1[i] = cent1[i];
}

// ---------------------------------------------------------------------------
// Kernel 2: blocks [0, BB) run FPS STAGE 2 (2048 -> 512, TOP-2) -> p2;
// blocks [BB, BB + M1*BB) each compute ONE sa1 center row h1[crow] and —
// when fuse_y2 != 0 — immediately the y2 row with k_y2's exact addition
// order, hidden under the stage-2 serial chain (R8/R9-proven).
// ---------------------------------------------------------------------------
__global__ __launch_bounds__(256) void k_fps2_sa1(
    const float2* __restrict__ x, const float* __restrict__ p1,
    const float* __restrict__ y1, const float* __restrict__ c1W,
    const float* __restrict__ c2W, const float* __restrict__ c2b,
    float* __restrict__ p2out, float* __restrict__ h1,
    float* __restrict__ y2, int fuse_y2)
{
    __shared__ float2 PTS2[M1];           // 16 KB stage2 points
    __shared__ float2 cent2[M2];          // 4 KB
    __shared__ uint4 slkA[2][4];
    __shared__ uint2 slkB[2][4];
    __shared__ int cnt;
    __shared__ int list[NN];              // 16 KB sa candidate list
    __shared__ float h1row[64];           // staged h1 row for fused y2
    int tid = threadIdx.x, lane = tid & 63, wv = tid >> 6;

    if (blockIdx.x < (unsigned)BB) {
        // -------------------- FPS stage 2, TOP-2 --------------------------
        const float2* p1b = (const float2*)(p1 + (size_t)blockIdx.x * M1 * 2);
        for (int i = tid; i < M1; i += 256) PTS2[i] = p1b[i];
        __syncthreads();                  // PTS2 complete
        fps_core<M2, M1 / 256, false>(PTS2, PTS2, cent2, slkA, slkB, tid, lane, wv);
        __syncthreads();                  // cent2 complete
        float2* o2 = (float2*)(p2out + (size_t)blockIdx.x * M2 * 2);
        for (int i = tid; i < M2; i += 256) o2[i] = cent2[i];
        return;
    }

    // -------------------- sa1: one center per block -----------------------
    int idx = (int)blockIdx.x - BB;       // 0 .. M1*BB-1
    int b = idx >> 11;                    // / M1 (M1 == 2048)
    size_t crow = (size_t)idx;            // == b*M1 + (idx % M1)
    if (tid == 0) cnt = 0;
    __syncthreads();
    float cx = p1[crow * 2], cy = p1[crow * 2 + 1];
    const float2* cp = x + (size_t)b * NN;
    for (int j = tid; j < NN; j += 256) {
        float2 pj = cp[j];
        float d2 = d2_exact(pj.x - cx, pj.y - cy);
        if (d2 <= 0.25f) { int t = atomicAdd(&cnt, 1); list[t] = j; }
    }
    __syncthreads();
    int n = cnt;
    for (int f = tid; f < 64; f += 256) {
        float m = -3.0e38f;
        for (int t = 0; t < n; ++t)
            m = fmaxf(m, y1[((size_t)b * NN + list[t]) * 64 + f]);
        float ct = cx * c1W[(size_t)65 * 64 + f] + cy * c1W[(size_t)66 * 64 + f];
        float h1v = m - ct;
        if (fuse_y2) h1row[f] = h1v;
        else h1[crow * 64 + f] = h1v;
    }
    if (fuse_y2) {                        // uniform kernel arg -> safe barrier
        __syncthreads();                  // h1row complete
        // exact k_y2 arithmetic/order: (bb + px*W64) + py*W65, then c=0..63
        for (int f = tid; f < 128; f += 256) {
            float acc = c2b[f] + cx * c2W[64 * 128 + f]
                      + cy * c2W[65 * 128 + f];
#pragma unroll
            for (int c = 0; c < 64; ++c) acc += h1row[c] * c2W[c * 128 + f];
            y2[crow * 128 + f] = acc;
        }
    }
}

// ---------------------------------------------------------------------------
// Set abstraction (stage 2): h[i,f] = max_{j: d2<=r2} y[j,f] - ctr_i @ W_rel.
// ---------------------------------------------------------------------------
__global__ __launch_bounds__(256) void k_sa(
    const float2* __restrict__ candpos, const float* __restrict__ y,
    const float* __restrict__ ctr, const float* __restrict__ W,
    int NP, int F, int relrow, float r2, float* __restrict__ hout)
{
    __shared__ int cnt;
    __shared__ int list[4096];
    int tid = threadIdx.x;
    int b = blockIdx.y;
    size_t crow = (size_t)b * gridDim.x + blockIdx.x;
    if (tid == 0) cnt = 0;
    __syncthreads();
    float cx = ctr[crow * 2], cy = ctr[crow * 2 + 1];
    const float2* cp = candpos + (size_t)b * NP;
    for (int j = tid; j < NP; j += 256) {
        float2 pj = cp[j];
        float d2 = d2_exact(pj.x - cx, pj.y - cy);
        if (d2 <= r2) { int t = atomicAdd(&cnt, 1); list[t] = j; }
    }
    __syncthreads();
    int n = cnt;
    for (int f = tid; f < F; f += 256) {
        float m = -3.0e38f;
        for (int t = 0; t < n; ++t)
            m = fmaxf(m, y[((size_t)b * NP + list[t]) * F + f]);
        float ct = cx * W[(size_t)relrow * F + f] + cy * W[(size_t)(relrow + 1) * F + f];
        hout[crow * F + f] = m - ct;
    }
}

// ---------------------------------------------------------------------------
// y2[j,f] = h1_j @ c2W[0:64] + pos_j @ c2W[64:66] + c2b  (fallback only)
// ---------------------------------------------------------------------------
__global__ __launch_bounds__(128) void k_y2(
    const float* __restrict__ h1, const float* __restrict__ p1,
    const float* __restrict__ W, const float* __restrict__ bb,
    float* __restrict__ y2)
{
    __shared__ float sh[64];
    size_t row = blockIdx.x;
    int f = threadIdx.x;
    if (f < 64) sh[f] = h1[row * 64 + f];
    __syncthreads();
    float acc = bb[f] + p1[row * 2] * W[64 * 128 + f]
              + p1[row * 2 + 1] * W[65 * 128 + f];
#pragma unroll
    for (int c = 0; c < 64; ++c) acc += sh[c] * W[c * 128 + f];
    y2[row * 128 + f] = acc;
}

// ---------------------------------------------------------------------------
// g[i,f] = [h2_i, pos_i] @ c3W + c3b; partial max over 8 rows/thread.
// ---------------------------------------------------------------------------
__global__ __launch_bounds__(256) void k_g(
    const float* __restrict__ h2, const float* __restrict__ p2,
    const float* __restrict__ W3, const float* __restrict__ b3,
    float* __restrict__ part)
{
    int f = blockIdx.x * 256 + threadIdx.x;
    int b = blockIdx.z;
    int i0 = blockIdx.y * 8;
    float acc[8];
    float bbv = b3[f];
#pragma unroll
    for (int ii = 0; ii < 8; ++ii) acc[ii] = bbv;
    const float* hrow = h2 + ((size_t)b * M2 + i0) * 128;
    for (int c = 0; c < 128; ++c) {
        float w = W3[(size_t)c * 1024 + f];
#pragma unroll
        for (int ii = 0; ii < 8; ++ii) acc[ii] += hrow[ii * 128 + c] * w;
    }
    float wx = W3[(size_t)128 * 1024 + f];
    float wy = W3[(size_t)129 * 1024 + f];
    const float* prow = p2 + ((size_t)b * M2 + i0) * 2;
    float m = -3.0e38f;
#pragma unroll
    for (int ii = 0; ii < 8; ++ii) {
        float g = acc[ii] + prow[ii * 2] * wx + prow[ii * 2 + 1] * wy;
        m = fmaxf(m, g);
    }
    part[((size_t)b * 64 + blockIdx.y) * 1024 + f] = m;
}

__global__ __launch_bounds__(256) void k_gmax(const float* __restrict__ part,
                                              float* __restrict__ outg)
{
    int f = blockIdx.x * 256 + threadIdx.x;   // 0..4095
    int b = f >> 10, fl = f & 1023;
    float m = -3.0e38f;
#pragma unroll 8
    for (int ig = 0; ig < 64; ++ig)
        m = fmaxf(m, part[((size_t)b * 64 + ig) * 1024 + fl]);
    outg[f] = m;
}

extern "C" void kernel_launch(void* const* d_in, const int* in_sizes, int n_in,
                              void* d_out, int out_size, void* d_ws, size_t ws_size,
                              hipStream_t stream)
{
    const float* x    = (const float*)d_in[0];
    const float* zon  = (const float*)d_in[1];
    const float* lfW1 = (const float*)d_in[2];
    const float* lfb1 = (const float*)d_in[3];
    const float* lfW2 = (const float*)d_in[4];
    const float* lfb2 = (const float*)d_in[5];
    const float* c1W  = (const float*)d_in[6];
    const float* c1b  = (const float*)d_in[7];
    const float* c2W  = (const float*)d_in[8];
    const float* c2b  = (const float*)d_in[9];
    const float* c3W  = (const float*)d_in[10];
    const float* c3b  = (const float*)d_in[11];
    float* out = (float*)d_out;

    // Sizes (bytes)
    const size_t szY1 = (size_t)BB * NN * 64 * 4;    // 4 MB
    const size_t szP1 = (size_t)BB * M1 * 2 * 4;
    const size_t szH1 = (size_t)BB * M1 * 64 * 4;    // 2 MB
    const size_t szY2 = (size_t)BB * M1 * 128 * 4;   // 4 MB
    const size_t szP2 = (size_t)BB * M2 * 2 * 4;
    const size_t szH2 = (size_t)BB * M2 * 128 * 4;   // 1 MB

    // Fused layout needs y2 NOT aliasing y1 (sa1 blocks read y1 while y2 is
    // written). Fall back to the R8 layout + k_y2 when ws is too small.
    bool fuse = ws_size >= szY1 + szP1 + szY2 + szP2 + szH2;

    char* w = (char*)d_ws;
    float* y1 = (float*)w;                     w += szY1;   // also reused: part
    float* p1 = (float*)w;                     w += szP1;
    float *h1, *y2;
    if (fuse) {
        h1 = nullptr;
        y2 = (float*)w;                        w += szY2;
    } else {
        h1 = (float*)w;                        w += szH1;
        y2 = y1;                               // R8 alias (y1 dead by k_y2)
    }
    float* p2 = (float*)w;                     w += szP2;
    float* h2 = (float*)w;                     w += szH2;
    float* part = y1;                          // y1 dead after kernel 2

    // Stage-1 FPS (blocks 0..3, top-3) overlaps lf/y1 (blocks 4..4099).
    k_fps1<<<BB + BB * NN / 4, 256, 0, stream>>>(
        (const float2*)x, p1, zon, lfW1, lfb1, lfW2, lfb2, c1W, c1b, out, y1);
    // Stage-2 FPS (blocks 0..3, top-2) overlaps sa1 (+fused y2).
    k_fps2_sa1<<<BB + BB * M1, 256, 0, stream>>>(
        (const float2*)x, p1, y1, c1W, c2W, c2b, p2,
        fuse ? p1 /*unused*/ : h1, y2, fuse ? 1 : 0);
    if (!fuse)
        k_y2<<<BB * M1, 128, 0, stream>>>(h1, p1, c2W, c2b, y2);
    k_sa<<<dim3(M2, BB), 256, 0, stream>>>((const float2*)p1, y2, p2, c2W,
                                           M1, 128, 64, 1.0f, h2);
    k_g<<<dim3(4, 64, BB), 256, 0, stream>>>(h2, p2, c3W, c3b, part);
    k_gmax<<<16, 256, 0, stream>>>(part, out + (size_t)BB * NN * 64);
}